// Round 1
// 18034.854 us; speedup vs baseline: 3.0284x; 3.0284x over previous
//
#include <hip/hip_runtime.h>
#include <cmath>

typedef __attribute__((ext_vector_type(8))) short short8;
typedef __attribute__((ext_vector_type(4))) float floatx4;
typedef unsigned long long u64;

#define GPTR(p) ((const __attribute__((address_space(1))) void*)(p))
#define LPTR(p) ((__attribute__((address_space(3))) void*)(p))

__device__ unsigned int g_bar;   // monotonic device barrier counter (reset by cast_pack)

__device__ __forceinline__ unsigned short f2bf(float f) {
  union { float f; unsigned u; } v; v.f = f;
  unsigned r = (v.u + 0x7fffu + ((v.u >> 16) & 1u)) >> 16;
  return (unsigned short)r;
}
__device__ __forceinline__ float sigm_(float x) { return 1.0f / (1.0f + __expf(-x)); }
__device__ __forceinline__ float tanh_(float x) { return 1.0f - 2.0f / (__expf(2.0f * x) + 1.0f); }

// 16B coherent load from the agent coherence point (bypasses L1/L2): two 8B relaxed
// agent-scope atomic loads. Compiler tracks these as normal loads (waitcnt handled).
__device__ __forceinline__ short8 ald16(const u64* p) {
  union { u64 q[2]; short8 v; } u;
  u.q[0] = __hip_atomic_load(p,     __ATOMIC_RELAXED, __HIP_MEMORY_SCOPE_AGENT);
  u.q[1] = __hip_atomic_load(p + 1, __ATOMIC_RELAXED, __HIP_MEMORY_SCOPE_AGENT);
  return u.v;
}

// ---------------- cast / pack kernel ----------------
__global__ void cast_pack(const float* __restrict__ states,
                          const float* __restrict__ Win,
                          const float* __restrict__ Wih,
                          const float* __restrict__ Whh,
                          const float* __restrict__ bih,
                          const float* __restrict__ bhh,
                          unsigned short* __restrict__ sb,
                          unsigned short* __restrict__ wpb,
                          unsigned short* __restrict__ wib,
                          unsigned short* __restrict__ whb,
                          float* __restrict__ bsum) {
  if (blockIdx.x == 0 && threadIdx.x == 0) g_bar = 0u;   // reset barrier each launch
  const int NS = 8388608, NW = 524288, NI = 8388608, NH = 8388608, NB = 8192;
  const int total = NS + NW + NI + NH + NB;
  for (int i = blockIdx.x * blockDim.x + threadIdx.x; i < total;
       i += gridDim.x * blockDim.x) {
    int j = i;
    if (j < NS) { sb[j] = f2bf(states[j]); continue; }
    j -= NS;
    if (j < NW) { int r = j >> 9, c = j & 511;
                  wpb[j] = (r < 960) ? f2bf(Win[r * 512 + c]) : (unsigned short)0; continue; }
    j -= NW;
    if (j < NI) { wib[j] = f2bf(Wih[j]); continue; }
    j -= NI;
    if (j < NH) { whb[j] = f2bf(Whh[j]); continue; }
    j -= NH;
    bsum[j] = bih[j] + bhh[j];
  }
}

// ---------------- m97-style bf16 GEMM, C = A(M,K) * B(N,K)^T ----------------
template <int MODE>
__global__ __launch_bounds__(256) void gemm_bt(
    const unsigned short* __restrict__ A, const unsigned short* __restrict__ B,
    int K, int N,
    float* __restrict__ outF, unsigned short* __restrict__ outH,
    const float* __restrict__ bias,
    const float* __restrict__ emb, const int* __restrict__ aidx) {
  __shared__ unsigned short As[128 * 32];
  __shared__ unsigned short Bs[128 * 32];
  const int tid = threadIdx.x;
  const int wave = tid >> 6, lane = tid & 63;
  const int quad = lane >> 4, l16 = lane & 15;
  const int wm = (wave & 1) * 64, wn = (wave >> 1) * 64;
  const int m0 = blockIdx.x * 128, n0 = blockIdx.y * 128;
  floatx4 acc[4][4] = {};
  const int r0 = tid >> 2, c0 = (tid & 3) * 8;
  const unsigned short* Ag0 = A + (size_t)(m0 + r0) * K + c0;
  const unsigned short* Ag1 = A + (size_t)(m0 + 64 + r0) * K + c0;
  const unsigned short* Bg0 = B + (size_t)(n0 + r0) * K + c0;
  const unsigned short* Bg1 = B + (size_t)(n0 + 64 + r0) * K + c0;
  for (int kt = 0; kt < K; kt += 32) {
    __builtin_amdgcn_global_load_lds(GPTR(Ag0 + kt), LPTR(&As[tid * 8]), 16, 0, 0);
    __builtin_amdgcn_global_load_lds(GPTR(Ag1 + kt), LPTR(&As[(tid + 256) * 8]), 16, 0, 0);
    __builtin_amdgcn_global_load_lds(GPTR(Bg0 + kt), LPTR(&Bs[tid * 8]), 16, 0, 0);
    __builtin_amdgcn_global_load_lds(GPTR(Bg1 + kt), LPTR(&Bs[(tid + 256) * 8]), 16, 0, 0);
    __syncthreads();
    short8 af[4], bf[4];
#pragma unroll
    for (int i = 0; i < 4; ++i)
      af[i] = *(const short8*)&As[(wm + i * 16 + l16) * 32 + quad * 8];
#pragma unroll
    for (int j = 0; j < 4; ++j)
      bf[j] = *(const short8*)&Bs[(wn + j * 16 + l16) * 32 + quad * 8];
#pragma unroll
    for (int i = 0; i < 4; ++i)
#pragma unroll
      for (int j = 0; j < 4; ++j)
        acc[i][j] = __builtin_amdgcn_mfma_f32_16x16x32_bf16(af[i], bf[j], acc[i][j], 0, 0, 0);
    __syncthreads();
  }
#pragma unroll
  for (int i = 0; i < 4; ++i) {
    const int mrow = m0 + wm + i * 16 + quad * 4;
#pragma unroll
    for (int j = 0; j < 4; ++j) {
      const int n = n0 + wn + j * 16 + l16;
#pragma unroll
      for (int r = 0; r < 4; ++r) {
        const int m = mrow + r;
        float v = acc[i][j][r];
        if (MODE == 0) {
          outF[(size_t)m * N + n] = v + bias[n];
        } else {
          float o;
          if (n < 960) { o = v + bias[n]; o = o > 0.f ? o : 0.f; }
          else         { o = emb[aidx[m] * 64 + (n - 960)]; }
          outH[(size_t)m * 1024 + n] = f2bf(o);
        }
      }
    }
  }
}

// ---------------- LSTM recurrence (one layer) ----------------
// 64 wgs x 512 threads. wg owns 16 h-cols -> 64 W_hh rows (4 gates x 16 cols), in LDS.
// Per step: gates(32x16slice) = h_{s-1} @ Whh_slice^T via MFMA, + xg[s] (bias folded),
// pointwise update, h written via agent-coherent stores. Device barrier: monotonic
// counter, relaxed atomics only — NO wbl2/inv cache maintenance in the loop.
__global__ __launch_bounds__(512) void lstm_rec(
    const unsigned short* __restrict__ Wh,   // (4096,1024) bf16 this layer
    const float* __restrict__ xg,            // (16384,4096) fp32, bias included
    unsigned short* __restrict__ hbf,        // (16384,1024) bf16 h outputs
    float* __restrict__ hs, float* __restrict__ cs,
    float* __restrict__ rnn,                 // nullptr for layer 0
    unsigned int base)                       // barrier count at entry (0 or 64*511)
{
  __shared__ unsigned short Wlds[64 * 1032];   // 4 units x 16 rows, stride 1032 (pad)
  __shared__ float gbuf[4 * 16 * 33];
  const int tid = threadIdx.x;
  const int wg = blockIdx.x;
  const int J0 = wg * 16;
  const int wave = tid >> 6, lane = tid & 63, quad = lane >> 4, l16 = lane & 15;
  const int cg = wave >> 1, wh = wave & 1;   // unit (col-quad group), batch-half

  // stage W_hh slice: local row r = u*16 + (g*4+uj) <- global row g*1024 + J0 + u*4 + uj
  for (int idx = tid; idx < 64 * 128; idx += 512) {
    const int r = idx >> 7, c = (idx & 127) << 3;
    const int u = r >> 4, rr = r & 15;
    const int grow = (rr >> 2) * 1024 + J0 + u * 4 + (rr & 3);
    *(short8*)&Wlds[r * 1032 + c] = *(const short8*)&Wh[(size_t)grow * 1024 + c];
  }

  // pointwise mapping: 16 consecutive lanes = 16 consecutive cols (64B-coalesced)
  const int ub = tid >> 4;          // batch 0..31
  const int jj = tid & 15;          // col within wg slice
  const int col = J0 + jj;
  const int pu = jj >> 2, puj = jj & 3;
  float cstate = 0.f;
  const size_t xrow = (size_t)ub * 512;

  float p[4];
#pragma unroll
  for (int g = 0; g < 4; ++g) p[g] = xg[(xrow + 0) * 4096 + g * 1024 + col];
  __syncthreads();

  for (int s = 0; s < 512; ++s) {
    if (s > 0) {
      // ---- device barrier (h_{s-1} visible at coherence point) ----
      asm volatile("s_waitcnt vmcnt(0)" ::: "memory");   // my stores reached IF
      __syncthreads();                                   // whole wg drained
      if (tid == 0)
        __hip_atomic_fetch_add(&g_bar, 1u, __ATOMIC_RELAXED, __HIP_MEMORY_SCOPE_AGENT);
      // prefetch this step's xg while the barrier resolves
#pragma unroll
      for (int g = 0; g < 4; ++g) p[g] = xg[(xrow + s) * 4096 + g * 1024 + col];
      if (tid == 0) {
        const unsigned tgt = base + 64u * (unsigned)s;
        while (__hip_atomic_load(&g_bar, __ATOMIC_RELAXED, __HIP_MEMORY_SCOPE_AGENT) < tgt)
          __builtin_amdgcn_s_sleep(1);
      }
      __syncthreads();
      asm volatile("" ::: "memory");

      // ---- gates slice = h_{s-1} @ Whh_slice^T (coherent A-loads) ----
      floatx4 a0 = {}, a1 = {};
      const int m = wh * 16 + l16;
      const u64* Arow = (const u64*)(hbf + ((size_t)m * 512 + (s - 1)) * 1024);
      const unsigned short* Brow = &Wlds[(cg * 16 + l16) * 1032];
#pragma unroll
      for (int ks = 0; ks < 32; ks += 2) {
        short8 av0 = ald16(Arow + ks * 8 + quad * 2);
        short8 bv0 = *(const short8*)&Brow[ks * 32 + quad * 8];
        a0 = __builtin_amdgcn_mfma_f32_16x16x32_bf16(av0, bv0, a0, 0, 0, 0);
        short8 av1 = ald16(Arow + (ks + 1) * 8 + quad * 2);
        short8 bv1 = *(const short8*)&Brow[(ks + 1) * 32 + quad * 8];
        a1 = __builtin_amdgcn_mfma_f32_16x16x32_bf16(av1, bv1, a1, 0, 0, 0);
      }
      // C/D: col=lane&15 (=slice row n), row=quad*4+reg (=batch within half)
#pragma unroll
      for (int r = 0; r < 4; ++r)
        gbuf[cg * 528 + l16 * 33 + wh * 16 + quad * 4 + r] = a0[r] + a1[r];
      __syncthreads();
#pragma unroll
      for (int g = 0; g < 4; ++g)
        p[g] += gbuf[pu * 528 + (g * 4 + puj) * 33 + ub];
    }
    const float iv = sigm_(p[0]), fv = sigm_(p[1]);
    const float gv = tanh_(p[2]), ov = sigm_(p[3]);
    cstate = fv * cstate + iv * gv;
    const float hv = ov * tanh_(cstate);
    const size_t ob = (xrow + s) * 1024 + col;
    // h exchange: write-through to coherence point (no L2 dirty state)
    __hip_atomic_store(&hbf[ob], f2bf(hv), __ATOMIC_RELAXED, __HIP_MEMORY_SCOPE_AGENT);
    // pure outputs: nontemporal, keep L2 clean
    __builtin_nontemporal_store(hv, &hs[ob]);
    __builtin_nontemporal_store(cstate, &cs[ob]);
    if (rnn) __builtin_nontemporal_store(hv, &rnn[ob]);
  }
}

extern "C" void kernel_launch(void* const* d_in, const int* in_sizes, int n_in,
                              void* d_out, int out_size, void* d_ws, size_t ws_size,
                              hipStream_t stream) {
  const float* states = (const float*)d_in[0];
  const int*   aidx   = (const int*)d_in[1];
  const float* Win    = (const float*)d_in[2];
  const float* bin    = (const float*)d_in[3];
  const float* emb    = (const float*)d_in[4];
  const float* Wih    = (const float*)d_in[5];
  const float* Whh    = (const float*)d_in[6];
  const float* bih    = (const float*)d_in[7];
  const float* bhh    = (const float*)d_in[8];
  float* out = (float*)d_out;
  const size_t BSH = 32ull * 512 * 1024;
  float* rnn_out = out;
  float* hs0 = out + BSH;
  float* hs1 = out + 2 * BSH;
  float* cs0 = out + 3 * BSH;
  float* cs1 = out + 4 * BSH;

  char* w = (char*)d_ws;
  unsigned short* sb  = (unsigned short*)w; w += 16777216;   // states bf16
  unsigned short* wpb = (unsigned short*)w; w += 1048576;    // W_in padded bf16 (1024x512)
  unsigned short* wib = (unsigned short*)w; w += 16777216;   // W_ih bf16 (2 layers)
  unsigned short* whb = (unsigned short*)w; w += 16777216;   // W_hh bf16 (2 layers)
  float*          bsum= (float*)w;          w += 32768;      // b_ih+b_hh (2x4096)
  unsigned short* x0  = (unsigned short*)w; w += 33554432;   // LSTM-0 input bf16
  unsigned short* hbf = (unsigned short*)w; w += 33554432;   // per-layer h bf16
  float*          xg  = (float*)w;                           // (16384x4096) fp32

  hipLaunchKernelGGL(cast_pack, dim3(4096), dim3(256), 0, stream,
                     states, Win, Wih, Whh, bih, bhh, sb, wpb, wib, whb, bsum);

  // x0 = [relu(states@Win^T + bin), emb[idx]]  (M=16384,N=1024,K=512)
  hipLaunchKernelGGL((gemm_bt<1>), dim3(128, 8), dim3(256), 0, stream,
                     sb, wpb, 512, 1024, (float*)nullptr, x0, bin, emb, aidx);

  // xg0 = x0 @ W_ih0^T + (b_ih0 + b_hh0)
  hipLaunchKernelGGL((gemm_bt<0>), dim3(128, 32), dim3(256), 0, stream,
                     x0, wib, 1024, 4096, xg, (unsigned short*)nullptr, bsum,
                     (const float*)nullptr, (const int*)nullptr);

  // layer-0 recurrence (cooperative: guarantees co-residency of 64 wgs)
  {
    const unsigned short* whL = whb;
    const float* xgp = xg;
    unsigned short* hbfp = hbf;
    float* hsp = hs0; float* csp = cs0; float* rnnp = nullptr;
    unsigned int basev = 0u;
    void* args[] = { &whL, &xgp, &hbfp, &hsp, &csp, &rnnp, &basev };
    hipLaunchCooperativeKernel((void*)lstm_rec, dim3(64), dim3(512), args, 0, stream);
  }

  // xg1 = h0_bf16 @ W_ih1^T + (b_ih1 + b_hh1)
  hipLaunchKernelGGL((gemm_bt<0>), dim3(128, 32), dim3(256), 0, stream,
                     hbf, wib + 4194304, 1024, 4096, xg, (unsigned short*)nullptr,
                     bsum + 4096, (const float*)nullptr, (const int*)nullptr);

  // layer-1 recurrence; also writes rnn_out
  {
    const unsigned short* whL = whb + 4194304;
    const float* xgp = xg;
    unsigned short* hbfp = hbf;
    float* hsp = hs1; float* csp = cs1; float* rnnp = rnn_out;
    unsigned int basev = 64u * 511u;
    void* args[] = { &whL, &xgp, &hbfp, &hsp, &csp, &rnnp, &basev };
    hipLaunchCooperativeKernel((void*)lstm_rec, dim3(64), dim3(512), args, 0, stream);
  }
}

// Round 2
// 10834.609 us; speedup vs baseline: 5.0409x; 1.6646x over previous
//
#include <hip/hip_runtime.h>
#include <cmath>

typedef __attribute__((ext_vector_type(8))) short short8;
typedef __attribute__((ext_vector_type(4))) float floatx4;
typedef unsigned long long u64;

#define GPTR(p) ((const __attribute__((address_space(1))) void*)(p))
#define LPTR(p) ((__attribute__((address_space(3))) void*)(p))

// slot/flag device barrier state (re-zeroed by cast_pack each launch)
__device__ unsigned int g_slots[64];
__device__ unsigned int g_go;

__device__ __forceinline__ unsigned short f2bf(float f) {
  union { float f; unsigned u; } v; v.f = f;
  unsigned r = (v.u + 0x7fffu + ((v.u >> 16) & 1u)) >> 16;
  return (unsigned short)r;
}
__device__ __forceinline__ float sigm_(float x) { return 1.0f / (1.0f + __expf(-x)); }
__device__ __forceinline__ float tanh_(float x) { return 1.0f - 2.0f / (__expf(2.0f * x) + 1.0f); }

// ---------------- cast / pack kernel ----------------
__global__ void cast_pack(const float* __restrict__ states,
                          const float* __restrict__ Win,
                          const float* __restrict__ Wih,
                          const float* __restrict__ Whh,
                          const float* __restrict__ bih,
                          const float* __restrict__ bhh,
                          unsigned short* __restrict__ sb,
                          unsigned short* __restrict__ wpb,
                          unsigned short* __restrict__ wib,
                          unsigned short* __restrict__ whb,
                          float* __restrict__ bsum) {
  if (blockIdx.x == 0) {
    if (threadIdx.x < 64) g_slots[threadIdx.x] = 0u;
    if (threadIdx.x == 64) g_go = 0u;
  }
  const int NS = 8388608, NW = 524288, NI = 8388608, NH = 8388608, NB = 8192;
  const int total = NS + NW + NI + NH + NB;
  for (int i = blockIdx.x * blockDim.x + threadIdx.x; i < total;
       i += gridDim.x * blockDim.x) {
    int j = i;
    if (j < NS) { sb[j] = f2bf(states[j]); continue; }
    j -= NS;
    if (j < NW) { int r = j >> 9, c = j & 511;
                  wpb[j] = (r < 960) ? f2bf(Win[r * 512 + c]) : (unsigned short)0; continue; }
    j -= NW;
    if (j < NI) { wib[j] = f2bf(Wih[j]); continue; }
    j -= NI;
    if (j < NH) { whb[j] = f2bf(Whh[j]); continue; }
    j -= NH;
    bsum[j] = bih[j] + bhh[j];
  }
}

// ---------------- m97-style bf16 GEMM, C = A(M,K) * B(N,K)^T ----------------
template <int MODE>
__global__ __launch_bounds__(256) void gemm_bt(
    const unsigned short* __restrict__ A, const unsigned short* __restrict__ B,
    int K, int N,
    float* __restrict__ outF, unsigned short* __restrict__ outH,
    const float* __restrict__ bias,
    const float* __restrict__ emb, const int* __restrict__ aidx) {
  __shared__ unsigned short As[128 * 32];
  __shared__ unsigned short Bs[128 * 32];
  const int tid = threadIdx.x;
  const int wave = tid >> 6, lane = tid & 63;
  const int quad = lane >> 4, l16 = lane & 15;
  const int wm = (wave & 1) * 64, wn = (wave >> 1) * 64;
  const int m0 = blockIdx.x * 128, n0 = blockIdx.y * 128;
  floatx4 acc[4][4] = {};
  const int r0 = tid >> 2, c0 = (tid & 3) * 8;
  const unsigned short* Ag0 = A + (size_t)(m0 + r0) * K + c0;
  const unsigned short* Ag1 = A + (size_t)(m0 + 64 + r0) * K + c0;
  const unsigned short* Bg0 = B + (size_t)(n0 + r0) * K + c0;
  const unsigned short* Bg1 = B + (size_t)(n0 + 64 + r0) * K + c0;
  for (int kt = 0; kt < K; kt += 32) {
    __builtin_amdgcn_global_load_lds(GPTR(Ag0 + kt), LPTR(&As[tid * 8]), 16, 0, 0);
    __builtin_amdgcn_global_load_lds(GPTR(Ag1 + kt), LPTR(&As[(tid + 256) * 8]), 16, 0, 0);
    __builtin_amdgcn_global_load_lds(GPTR(Bg0 + kt), LPTR(&Bs[tid * 8]), 16, 0, 0);
    __builtin_amdgcn_global_load_lds(GPTR(Bg1 + kt), LPTR(&Bs[(tid + 256) * 8]), 16, 0, 0);
    __syncthreads();
    short8 af[4], bf[4];
#pragma unroll
    for (int i = 0; i < 4; ++i)
      af[i] = *(const short8*)&As[(wm + i * 16 + l16) * 32 + quad * 8];
#pragma unroll
    for (int j = 0; j < 4; ++j)
      bf[j] = *(const short8*)&Bs[(wn + j * 16 + l16) * 32 + quad * 8];
#pragma unroll
    for (int i = 0; i < 4; ++i)
#pragma unroll
      for (int j = 0; j < 4; ++j)
        acc[i][j] = __builtin_amdgcn_mfma_f32_16x16x32_bf16(af[i], bf[j], acc[i][j], 0, 0, 0);
    __syncthreads();
  }
#pragma unroll
  for (int i = 0; i < 4; ++i) {
    const int mrow = m0 + wm + i * 16 + quad * 4;
#pragma unroll
    for (int j = 0; j < 4; ++j) {
      const int n = n0 + wn + j * 16 + l16;
#pragma unroll
      for (int r = 0; r < 4; ++r) {
        const int m = mrow + r;
        float v = acc[i][j][r];
        if (MODE == 0) {
          outF[(size_t)m * N + n] = v + bias[n];
        } else {
          float o;
          if (n < 960) { o = v + bias[n]; o = o > 0.f ? o : 0.f; }
          else         { o = emb[aidx[m] * 64 + (n - 960)]; }
          outH[(size_t)m * 1024 + n] = f2bf(o);
        }
      }
    }
  }
}

// ---------------- LSTM recurrence (one layer) ----------------
// 64 wgs x 512 threads. wg owns 16 h-cols -> 64 W_hh rows (4 gates x 16 cols), in LDS.
// h exchange: write-through agent-scope stores; reads are PLAIN CACHED loads (safe:
// each h row is read exactly once, one step after all writers passed the barrier, and
// dispatch-start acquire invalidates stale cross-kernel lines). Barrier: per-wg slot
// stores + wave-wide poll by wg0 + single go flag. No RMW contention, no cache ops.
__global__ __launch_bounds__(512) void lstm_rec(
    const unsigned short* __restrict__ Wh,   // (4096,1024) bf16 this layer
    const float* __restrict__ xg,            // (16384,4096) fp32, bias included
    unsigned short* __restrict__ hbf,        // (16384,1024) bf16 h outputs
    float* __restrict__ hs, float* __restrict__ cs,
    float* __restrict__ rnn,                 // nullptr for layer 0
    unsigned int base)                       // epoch base (0 for layer 0, 511 for layer 1)
{
  __shared__ unsigned short Wlds[64 * 1032];   // 4 units x 16 rows, stride 1032 (pad)
  __shared__ float gbuf[4 * 16 * 33];
  const int tid = threadIdx.x;
  const int wg = blockIdx.x;
  const int J0 = wg * 16;
  const int wave = tid >> 6, lane = tid & 63, quad = lane >> 4, l16 = lane & 15;
  const int cg = wave >> 1, wh = wave & 1;   // unit (col-quad group), batch-half

  // stage W_hh slice: local row r = u*16 + (g*4+uj) <- global row g*1024 + J0 + u*4 + uj
  for (int idx = tid; idx < 64 * 128; idx += 512) {
    const int r = idx >> 7, c = (idx & 127) << 3;
    const int u = r >> 4, rr = r & 15;
    const int grow = (rr >> 2) * 1024 + J0 + u * 4 + (rr & 3);
    *(short8*)&Wlds[r * 1032 + c] = *(const short8*)&Wh[(size_t)grow * 1024 + c];
  }

  // pointwise mapping: 16 consecutive lanes = 16 consecutive cols (64B-coalesced)
  const int ub = tid >> 4;          // batch 0..31
  const int jj = tid & 15;          // col within wg slice
  const int col = J0 + jj;
  const int pu = jj >> 2, puj = jj & 3;
  float cstate = 0.f;
  const size_t xrow = (size_t)ub * 512;

  float p[4];
#pragma unroll
  for (int g = 0; g < 4; ++g) p[g] = xg[(xrow + 0) * 4096 + g * 1024 + col];
  __syncthreads();

  for (int s = 0; s < 512; ++s) {
    if (s > 0) {
      const unsigned epoch = base + (unsigned)s;
      // ---- device barrier (h_{s-1} visible at coherence point) ----
      asm volatile("s_waitcnt vmcnt(0)" ::: "memory");   // my h stores acked at IF
      __syncthreads();                                   // whole wg drained
      if (tid == 0)
        __hip_atomic_store(&g_slots[wg], epoch, __ATOMIC_RELAXED, __HIP_MEMORY_SCOPE_AGENT);
      // prefetch this step's xg while the barrier resolves
#pragma unroll
      for (int g = 0; g < 4; ++g) p[g] = xg[(xrow + s) * 4096 + g * 1024 + col];
      if (wg == 0) {
        if (tid < 64) {
          for (;;) {
            unsigned v = __hip_atomic_load(&g_slots[tid], __ATOMIC_RELAXED, __HIP_MEMORY_SCOPE_AGENT);
            if (__all((int)(v >= epoch))) break;
            __builtin_amdgcn_s_sleep(1);
          }
          if (tid == 0)
            __hip_atomic_store(&g_go, epoch, __ATOMIC_RELAXED, __HIP_MEMORY_SCOPE_AGENT);
        }
      } else if (tid == 0) {
        while (__hip_atomic_load(&g_go, __ATOMIC_RELAXED, __HIP_MEMORY_SCOPE_AGENT) < epoch)
          __builtin_amdgcn_s_sleep(1);
      }
      __syncthreads();
      asm volatile("" ::: "memory");

      // ---- gates slice = h_{s-1} @ Whh_slice^T (cached A-loads, L1/L2 shared) ----
      floatx4 a0 = {}, a1 = {};
      const int m = wh * 16 + l16;
      const unsigned short* Au = hbf + ((size_t)m * 512 + (s - 1)) * 1024;
      const unsigned short* Brow = &Wlds[(cg * 16 + l16) * 1032];
#pragma unroll
      for (int ks = 0; ks < 32; ks += 2) {
        short8 av0 = *(const short8*)&Au[ks * 32 + quad * 8];
        short8 bv0 = *(const short8*)&Brow[ks * 32 + quad * 8];
        a0 = __builtin_amdgcn_mfma_f32_16x16x32_bf16(av0, bv0, a0, 0, 0, 0);
        short8 av1 = *(const short8*)&Au[(ks + 1) * 32 + quad * 8];
        short8 bv1 = *(const short8*)&Brow[(ks + 1) * 32 + quad * 8];
        a1 = __builtin_amdgcn_mfma_f32_16x16x32_bf16(av1, bv1, a1, 0, 0, 0);
      }
      // C/D: col=lane&15 (=slice row n), row=quad*4+reg (=batch within half)
#pragma unroll
      for (int r = 0; r < 4; ++r)
        gbuf[cg * 528 + l16 * 33 + wh * 16 + quad * 4 + r] = a0[r] + a1[r];
      __syncthreads();
#pragma unroll
      for (int g = 0; g < 4; ++g)
        p[g] += gbuf[pu * 528 + (g * 4 + puj) * 33 + ub];
    }
    const float iv = sigm_(p[0]), fv = sigm_(p[1]);
    const float gv = tanh_(p[2]), ov = sigm_(p[3]);
    cstate = fv * cstate + iv * gv;
    const float hv = ov * tanh_(cstate);
    const size_t ob = (xrow + s) * 1024 + col;
    // h exchange: write-through to coherence point first (longest-latency ack)
    __hip_atomic_store(&hbf[ob], f2bf(hv), __ATOMIC_RELAXED, __HIP_MEMORY_SCOPE_AGENT);
    // pure outputs: plain cached stores (ack from local L2; flushed at kernel end)
    hs[ob] = hv;
    cs[ob] = cstate;
    if (rnn) rnn[ob] = hv;
  }
}

extern "C" void kernel_launch(void* const* d_in, const int* in_sizes, int n_in,
                              void* d_out, int out_size, void* d_ws, size_t ws_size,
                              hipStream_t stream) {
  const float* states = (const float*)d_in[0];
  const int*   aidx   = (const int*)d_in[1];
  const float* Win    = (const float*)d_in[2];
  const float* bin    = (const float*)d_in[3];
  const float* emb    = (const float*)d_in[4];
  const float* Wih    = (const float*)d_in[5];
  const float* Whh    = (const float*)d_in[6];
  const float* bih    = (const float*)d_in[7];
  const float* bhh    = (const float*)d_in[8];
  float* out = (float*)d_out;
  const size_t BSH = 32ull * 512 * 1024;
  float* rnn_out = out;
  float* hs0 = out + BSH;
  float* hs1 = out + 2 * BSH;
  float* cs0 = out + 3 * BSH;
  float* cs1 = out + 4 * BSH;

  char* w = (char*)d_ws;
  unsigned short* sb  = (unsigned short*)w; w += 16777216;   // states bf16
  unsigned short* wpb = (unsigned short*)w; w += 1048576;    // W_in padded bf16 (1024x512)
  unsigned short* wib = (unsigned short*)w; w += 16777216;   // W_ih bf16 (2 layers)
  unsigned short* whb = (unsigned short*)w; w += 16777216;   // W_hh bf16 (2 layers)
  float*          bsum= (float*)w;          w += 32768;      // b_ih+b_hh (2x4096)
  unsigned short* x0  = (unsigned short*)w; w += 33554432;   // LSTM-0 input bf16
  unsigned short* hbf = (unsigned short*)w; w += 33554432;   // per-layer h bf16
  float*          xg  = (float*)w;                           // (16384x4096) fp32

  hipLaunchKernelGGL(cast_pack, dim3(4096), dim3(256), 0, stream,
                     states, Win, Wih, Whh, bih, bhh, sb, wpb, wib, whb, bsum);

  // x0 = [relu(states@Win^T + bin), emb[idx]]  (M=16384,N=1024,K=512)
  hipLaunchKernelGGL((gemm_bt<1>), dim3(128, 8), dim3(256), 0, stream,
                     sb, wpb, 512, 1024, (float*)nullptr, x0, bin, emb, aidx);

  // xg0 = x0 @ W_ih0^T + (b_ih0 + b_hh0)
  hipLaunchKernelGGL((gemm_bt<0>), dim3(128, 32), dim3(256), 0, stream,
                     x0, wib, 1024, 4096, xg, (unsigned short*)nullptr, bsum,
                     (const float*)nullptr, (const int*)nullptr);

  // layer-0 recurrence (cooperative: guarantees co-residency of 64 wgs)
  {
    const unsigned short* whL = whb;
    const float* xgp = xg;
    unsigned short* hbfp = hbf;
    float* hsp = hs0; float* csp = cs0; float* rnnp = nullptr;
    unsigned int basev = 0u;
    void* args[] = { &whL, &xgp, &hbfp, &hsp, &csp, &rnnp, &basev };
    hipLaunchCooperativeKernel((void*)lstm_rec, dim3(64), dim3(512), args, 0, stream);
  }

  // xg1 = h0_bf16 @ W_ih1^T + (b_ih1 + b_hh1)
  hipLaunchKernelGGL((gemm_bt<0>), dim3(128, 32), dim3(256), 0, stream,
                     hbf, wib + 4194304, 1024, 4096, xg, (unsigned short*)nullptr,
                     bsum + 4096, (const float*)nullptr, (const int*)nullptr);

  // layer-1 recurrence; also writes rnn_out (epochs continue at 512)
  {
    const unsigned short* whL = whb + 4194304;
    const float* xgp = xg;
    unsigned short* hbfp = hbf;
    float* hsp = hs1; float* csp = cs1; float* rnnp = rnn_out;
    unsigned int basev = 511u;
    void* args[] = { &whL, &xgp, &hbfp, &hsp, &csp, &rnnp, &basev };
    hipLaunchCooperativeKernel((void*)lstm_rec, dim3(64), dim3(512), args, 0, stream);
  }
}